// Round 1
// baseline (1347.496 us; speedup 1.0000x reference)
//
#include <hip/hip_runtime.h>

namespace {

constexpr int T = 10;
constexpr int D = 64;
constexpr int HEADS = 4;
constexpr int DH = 16;
constexpr int FF = 256;
constexpr int NLAYER = 3;
constexpr float EPS = 1e-5f;
constexpr int WAVES = 4;
constexpr int NBATCH = 16384;

__device__ __forceinline__ float wave_sum(float v) {
#pragma unroll
  for (int off = 32; off; off >>= 1) v += __shfl_xor(v, off);
  return v;
}

__global__ __launch_bounds__(WAVES * 64) void wtf_fused(
    const float* __restrict__ x, const float* __restrict__ embed_w,
    const float* __restrict__ embed_b, const float* __restrict__ ln1_g,
    const float* __restrict__ ln1_b, const float* __restrict__ qkv_w,
    const float* __restrict__ proj_w, const float* __restrict__ ln2_g,
    const float* __restrict__ ln2_b, const float* __restrict__ ffn_w1,
    const float* __restrict__ ffn_b1, const float* __restrict__ ffn_w2,
    const float* __restrict__ ffn_b2, const float* __restrict__ lnf_g,
    const float* __restrict__ lnf_b, const float* __restrict__ head_w,
    const float* __restrict__ head_b, float* __restrict__ out) {
  const int wave = threadIdx.x >> 6;
  const int lane = threadIdx.x & 63;
  const int batch = blockIdx.x * WAVES + wave;

  __shared__ float sA_all[WAVES][T][D];    // 10.0 KB: 64-wide staging
  __shared__ float sB_all[WAVES][T][FF];   // 40.0 KB: 192/256-wide staging
  float(*sA)[D] = sA_all[wave];
  float(*sB)[FF] = sB_all[wave];

  // ---------------- embed: h[t][lane] = x[t,:4] @ embed_w + embed_b --------
  {
    const float* xb = x + (size_t)batch * (T * 4);
    if (lane < T * 4) sB[0][lane] = xb[lane];
  }
  __syncthreads();
  float h[T];
  {
    const float w0 = embed_w[0 * D + lane], w1 = embed_w[1 * D + lane];
    const float w2 = embed_w[2 * D + lane], w3 = embed_w[3 * D + lane];
    const float bb = embed_b[lane];
#pragma unroll
    for (int t = 0; t < T; ++t) {
      const float4 xv = *(const float4*)&sB[0][t * 4];
      h[t] = fmaf(xv.x, w0, fmaf(xv.y, w1, fmaf(xv.z, w2, fmaf(xv.w, w3, bb))));
    }
  }
  __syncthreads();

  for (int li = 0; li < NLAYER; ++li) {
    // ---------------- LN1 -> sA ----------------
    {
      const float g = ln1_g[li * D + lane], b = ln1_b[li * D + lane];
#pragma unroll
      for (int t = 0; t < T; ++t) {
        const float v = h[t];
        const float s = wave_sum(v);
        const float s2 = wave_sum(v * v);
        const float m = s * (1.f / D);
        const float var = s2 * (1.f / D) - m * m;
        sA[t][lane] = (v - m) * rsqrtf(var + EPS) * g + b;
      }
    }
    __syncthreads();

    // ---------------- qkv: sB[t][0..191] = z @ qkv_w ----------------
    {
      const float* Wq = qkv_w + (size_t)li * D * 3 * D;
      float a0[T], a1[T], a2[T];
#pragma unroll
      for (int t = 0; t < T; ++t) a0[t] = a1[t] = a2[t] = 0.f;
      for (int dg = 0; dg < D / 4; ++dg) {
        float4 za[T];
#pragma unroll
        for (int t = 0; t < T; ++t) za[t] = *(const float4*)&sA[t][dg * 4];
#pragma unroll
        for (int dd = 0; dd < 4; ++dd) {
          const int d = dg * 4 + dd;
          const float w0 = Wq[d * 192 + lane];
          const float w1 = Wq[d * 192 + 64 + lane];
          const float w2 = Wq[d * 192 + 128 + lane];
#pragma unroll
          for (int t = 0; t < T; ++t) {
            const float zv = (&za[t].x)[dd];
            a0[t] = fmaf(zv, w0, a0[t]);
            a1[t] = fmaf(zv, w1, a1[t]);
            a2[t] = fmaf(zv, w2, a2[t]);
          }
        }
      }
#pragma unroll
      for (int t = 0; t < T; ++t) {
        sB[t][lane] = a0[t];
        sB[t][D + lane] = a1[t];
        sB[t][2 * D + lane] = a2[t];
      }
    }
    __syncthreads();

    // ------------- attention scores + softmax (lanes 0..39) -------------
    if (lane < HEADS * T) {
      const int head = lane / T, qt = lane % T;
      float q[DH];
#pragma unroll
      for (int r = 0; r < DH; r += 4) {
        const float4 qv = *(const float4*)&sB[qt][head * DH + r];
        q[r] = qv.x; q[r + 1] = qv.y; q[r + 2] = qv.z; q[r + 3] = qv.w;
      }
      float att[T];
#pragma unroll
      for (int kt = 0; kt < T; ++kt) {
        float s = 0.f;
#pragma unroll
        for (int r = 0; r < DH; r += 4) {
          const float4 kv = *(const float4*)&sB[kt][D + head * DH + r];
          s = fmaf(q[r], kv.x, s);
          s = fmaf(q[r + 1], kv.y, s);
          s = fmaf(q[r + 2], kv.z, s);
          s = fmaf(q[r + 3], kv.w, s);
        }
        att[kt] = (kt <= qt) ? s * 0.25f : -1e9f;  // 0.25 = dh^-0.5
      }
      float mx = att[0];
#pragma unroll
      for (int kt = 1; kt < T; ++kt) mx = fmaxf(mx, att[kt]);
      float sum = 0.f;
#pragma unroll
      for (int kt = 0; kt < T; ++kt) {
        att[kt] = __expf(att[kt] - mx);  // masked entries underflow to 0
        sum += att[kt];
      }
      const float inv = 1.f / sum;
      float* sAtt = &sA[0][0];  // reuse sA as att[4][10][10]
#pragma unroll
      for (int kt = 0; kt < T; ++kt) sAtt[head * 100 + qt * 10 + kt] = att[kt] * inv;
    }
    __syncthreads();

    // ------------- y = att @ v  (lane = channel = head*16 + r) -------------
    float yat[T];
    {
#pragma unroll
      for (int t = 0; t < T; ++t) yat[t] = 0.f;
      const int head = lane >> 4;
      const float* sAtt = &sA[0][0];
#pragma unroll
      for (int kt = 0; kt < T; ++kt) {
        const float vk = sB[kt][2 * D + lane];
#pragma unroll
        for (int qt = kt; qt < T; ++qt)
          yat[qt] = fmaf(sAtt[head * 100 + qt * 10 + kt], vk, yat[qt]);
      }
    }
    __syncthreads();
#pragma unroll
    for (int t = 0; t < T; ++t) sA[t][lane] = yat[t];
    __syncthreads();

    // ---------------- proj + residual ----------------
    {
      const float* Wp = proj_w + (size_t)li * D * D;
      float ap[T];
#pragma unroll
      for (int t = 0; t < T; ++t) ap[t] = 0.f;
      for (int cg = 0; cg < D / 4; ++cg) {
        float4 av[T];
#pragma unroll
        for (int t = 0; t < T; ++t) av[t] = *(const float4*)&sA[t][cg * 4];
#pragma unroll
        for (int cc = 0; cc < 4; ++cc) {
          const float w = Wp[(cg * 4 + cc) * D + lane];
#pragma unroll
          for (int t = 0; t < T; ++t) ap[t] = fmaf((&av[t].x)[cc], w, ap[t]);
        }
      }
#pragma unroll
      for (int t = 0; t < T; ++t) h[t] += ap[t];
    }
    __syncthreads();

    // ---------------- LN2 -> sA ----------------
    {
      const float g = ln2_g[li * D + lane], b = ln2_b[li * D + lane];
#pragma unroll
      for (int t = 0; t < T; ++t) {
        const float v = h[t];
        const float s = wave_sum(v);
        const float s2 = wave_sum(v * v);
        const float m = s * (1.f / D);
        const float var = s2 * (1.f / D) - m * m;
        sA[t][lane] = (v - m) * rsqrtf(var + EPS) * g + b;
      }
    }
    __syncthreads();

    // ---------------- ffn1 + exact gelu -> sB ----------------
    {
      const float* W1 = ffn_w1 + (size_t)li * D * FF;
      float f0[T], f1[T], f2[T], f3[T];
#pragma unroll
      for (int t = 0; t < T; ++t) f0[t] = f1[t] = f2[t] = f3[t] = 0.f;
      for (int dg = 0; dg < D / 4; ++dg) {
        float4 za[T];
#pragma unroll
        for (int t = 0; t < T; ++t) za[t] = *(const float4*)&sA[t][dg * 4];
#pragma unroll
        for (int dd = 0; dd < 4; ++dd) {
          const int d = dg * 4 + dd;
          const float w0 = W1[d * FF + lane];
          const float w1 = W1[d * FF + D + lane];
          const float w2 = W1[d * FF + 2 * D + lane];
          const float w3 = W1[d * FF + 3 * D + lane];
#pragma unroll
          for (int t = 0; t < T; ++t) {
            const float zv = (&za[t].x)[dd];
            f0[t] = fmaf(zv, w0, f0[t]);
            f1[t] = fmaf(zv, w1, f1[t]);
            f2[t] = fmaf(zv, w2, f2[t]);
            f3[t] = fmaf(zv, w3, f3[t]);
          }
        }
      }
      const float b0 = ffn_b1[li * FF + lane];
      const float b1 = ffn_b1[li * FF + D + lane];
      const float b2 = ffn_b1[li * FF + 2 * D + lane];
      const float b3 = ffn_b1[li * FF + 3 * D + lane];
#pragma unroll
      for (int t = 0; t < T; ++t) {
        float v0 = f0[t] + b0, v1 = f1[t] + b1, v2 = f2[t] + b2, v3 = f3[t] + b3;
        v0 = 0.5f * v0 * (1.f + erff(v0 * 0.70710678118f));
        v1 = 0.5f * v1 * (1.f + erff(v1 * 0.70710678118f));
        v2 = 0.5f * v2 * (1.f + erff(v2 * 0.70710678118f));
        v3 = 0.5f * v3 * (1.f + erff(v3 * 0.70710678118f));
        sB[t][lane] = v0;
        sB[t][D + lane] = v1;
        sB[t][2 * D + lane] = v2;
        sB[t][3 * D + lane] = v3;
      }
    }
    __syncthreads();

    // ---------------- ffn2 + residual ----------------
    {
      const float* W2 = ffn_w2 + (size_t)li * FF * D;
      float ac[T];
#pragma unroll
      for (int t = 0; t < T; ++t) ac[t] = 0.f;
      for (int jg = 0; jg < FF / 4; ++jg) {
        float4 zb[T];
#pragma unroll
        for (int t = 0; t < T; ++t) zb[t] = *(const float4*)&sB[t][jg * 4];
#pragma unroll
        for (int jj = 0; jj < 4; ++jj) {
          const float w = W2[(jg * 4 + jj) * D + lane];
#pragma unroll
          for (int t = 0; t < T; ++t) ac[t] = fmaf((&zb[t].x)[jj], w, ac[t]);
        }
      }
      const float bb = ffn_b2[li * D + lane];
#pragma unroll
      for (int t = 0; t < T; ++t) h[t] += ac[t] + bb;
    }
    __syncthreads();
  }

  // ---------------- final LN (last token only) + head ----------------
  {
    const float v = h[T - 1];
    const float s = wave_sum(v);
    const float s2 = wave_sum(v * v);
    const float m = s * (1.f / D);
    const float var = s2 * (1.f / D) - m * m;
    sA[0][lane] = (v - m) * rsqrtf(var + EPS) * lnf_g[lane] + lnf_b[lane];
  }
  __syncthreads();
  if (lane < 10) {
    float acc = head_b[lane];
#pragma unroll
    for (int d = 0; d < D; ++d) acc = fmaf(sA[0][d], head_w[d * 10 + lane], acc);
    out[(size_t)batch * 10 + lane] = acc;
  }
}

}  // namespace

extern "C" void kernel_launch(void* const* d_in, const int* in_sizes, int n_in,
                              void* d_out, int out_size, void* d_ws, size_t ws_size,
                              hipStream_t stream) {
  const float* x       = (const float*)d_in[0];
  const float* embed_w = (const float*)d_in[1];
  const float* embed_b = (const float*)d_in[2];
  const float* ln1_g   = (const float*)d_in[3];
  const float* ln1_b   = (const float*)d_in[4];
  const float* qkv_w   = (const float*)d_in[5];
  const float* proj_w  = (const float*)d_in[6];
  const float* ln2_g   = (const float*)d_in[7];
  const float* ln2_b   = (const float*)d_in[8];
  const float* ffn_w1  = (const float*)d_in[9];
  const float* ffn_b1  = (const float*)d_in[10];
  const float* ffn_w2  = (const float*)d_in[11];
  const float* ffn_b2  = (const float*)d_in[12];
  const float* lnf_g   = (const float*)d_in[13];
  const float* lnf_b   = (const float*)d_in[14];
  const float* head_w  = (const float*)d_in[15];
  const float* head_b  = (const float*)d_in[16];
  float* out = (float*)d_out;

  wtf_fused<<<dim3(NBATCH / WAVES), dim3(WAVES * 64), 0, stream>>>(
      x, embed_w, embed_b, ln1_g, ln1_b, qkv_w, proj_w, ln2_g, ln2_b,
      ffn_w1, ffn_b1, ffn_w2, ffn_b2, lnf_g, lnf_b, head_w, head_b, out);
}

// Round 4
// 584.125 us; speedup vs baseline: 2.3069x; 2.3069x over previous
//
#include <hip/hip_runtime.h>

namespace {

typedef __bf16 bf16x8 __attribute__((ext_vector_type(8)));
typedef float f32x4 __attribute__((ext_vector_type(4)));

constexpr int NB = 8;          // batches per block
constexpr int ROWS = 80;       // NB * T   (row = t*8 + b)
constexpr int MT = 5;          // M-tiles of 16 rows
constexpr int APAD = 72;       // bf16 staging row pitch (144 B, 16B-aligned)
constexpr int HPAD = 66;       // fp32 residual row pitch
constexpr int NBLK = 16384 / NB;

// ws bf16-fragment offsets (ushort elements)
constexpr int PROJF_OFF = 36864;   // 3 * 2 * 12 * 512
constexpr int F1F_OFF = 49152;
constexpr int F2F_OFF = 98304;
constexpr int WS_ELEMS = 147456;

__device__ __forceinline__ ushort f2b(float f) {  // RNE f32->bf16
  uint u = __float_as_uint(f);
  return (ushort)((u + 0x7fffu + ((u >> 16) & 1u)) >> 16);
}
__device__ __forceinline__ float b2f(ushort s) {
  return __uint_as_float((uint)s << 16);
}
__device__ __forceinline__ void unpack8(int4 v, float* f) {
  uint u;
  u = (uint)v.x; f[0] = __uint_as_float(u << 16); f[1] = __uint_as_float(u & 0xffff0000u);
  u = (uint)v.y; f[2] = __uint_as_float(u << 16); f[3] = __uint_as_float(u & 0xffff0000u);
  u = (uint)v.z; f[4] = __uint_as_float(u << 16); f[5] = __uint_as_float(u & 0xffff0000u);
  u = (uint)v.w; f[6] = __uint_as_float(u << 16); f[7] = __uint_as_float(u & 0xffff0000u);
}
__device__ __forceinline__ float gelu_f(float v) {  // 0.5v(1+erf(v/sqrt2))
  float ax = fabsf(v) * 0.70710678118f;
  float t = __builtin_amdgcn_rcpf(fmaf(0.3275911f, ax, 1.0f));
  float poly = t * fmaf(t, fmaf(t, fmaf(t, fmaf(t, 1.061405429f, -1.453152027f),
                                        1.421413741f), -0.284496736f), 0.254829592f);
  float erfv = fmaf(-poly, __expf(-ax * ax), 1.0f);
  erfv = copysignf(erfv, v);
  return 0.5f * v * (1.0f + erfv);
}
__device__ __forceinline__ f32x4 mfma_bf16(int4 a, int4 b, f32x4 c) {
  return __builtin_amdgcn_mfma_f32_16x16x32_bf16(
      __builtin_bit_cast(bf16x8, a), __builtin_bit_cast(bf16x8, b), c, 0, 0, 0);
}

// ---------------- weight prep: fp32 row-major -> bf16 B-fragment layout ----
__global__ __launch_bounds__(256) void prep_weights(
    const float* __restrict__ qkv_w, const float* __restrict__ proj_w,
    const float* __restrict__ ffn_w1, const float* __restrict__ ffn_w2,
    ushort* __restrict__ ws) {
  int idx = blockIdx.x * 256 + threadIdx.x;
  if (idx >= WS_ELEMS) return;
  const float* src;
  int N, Ksz, lstride, base;
  if (idx < PROJF_OFF) { src = qkv_w; N = 192; Ksz = 64; lstride = 12288; base = idx; }
  else if (idx < F1F_OFF) { src = proj_w; N = 64; Ksz = 64; lstride = 4096; base = idx - PROJF_OFF; }
  else if (idx < F2F_OFF) { src = ffn_w1; N = 256; Ksz = 64; lstride = 16384; base = idx - F1F_OFF; }
  else { src = ffn_w2; N = 64; Ksz = 256; lstride = 16384; base = idx - F2F_OFF; }
  int layer = base / lstride, rem = base % lstride;
  int ntk = N / 16;
  int kt = rem / (ntk * 512); rem %= (ntk * 512);
  int nt = rem / 512;
  int lane = (rem % 512) / 8, j = rem % 8;
  int k = kt * 32 + (lane >> 4) * 8 + j;
  int n = nt * 16 + (lane & 15);
  ws[idx] = f2b(src[(size_t)layer * Ksz * N + (size_t)k * N + n]);
}

// ---------------- LayerNorm: hres row -> bf16 staging -----------------------
__device__ __forceinline__ void ln_phase(const float (*hres)[HPAD], ushort (*dst)[APAD],
                                         const float* g, const float* b, int tid) {
  if (tid < ROWS) {
    const float* row = hres[tid];
    float s = 0.f, s2 = 0.f;
#pragma unroll
    for (int i = 0; i < 64; ++i) { float v = row[i]; s += v; s2 = fmaf(v, v, s2); }
    float m = s * 0.015625f;
    float rstd = rsqrtf(s2 * 0.015625f - m * m + 1e-5f);
#pragma unroll
    for (int i = 0; i < 32; ++i) {
      float v0 = (row[2 * i] - m) * rstd * g[2 * i] + b[2 * i];
      float v1 = (row[2 * i + 1] - m) * rstd * g[2 * i + 1] + b[2 * i + 1];
      *(uint*)&dst[tid][2 * i] = (uint)f2b(v0) | ((uint)f2b(v1) << 16);
    }
  }
}

__global__ __launch_bounds__(256) void wtf_mfma(
    const float* __restrict__ x, const float* __restrict__ embed_w,
    const float* __restrict__ embed_b, const float* __restrict__ ln1_g,
    const float* __restrict__ ln1_b, const float* __restrict__ ln2_g,
    const float* __restrict__ ln2_b, const float* __restrict__ ffn_b1,
    const float* __restrict__ ffn_b2, const float* __restrict__ lnf_g,
    const float* __restrict__ lnf_b, const float* __restrict__ head_w,
    const float* __restrict__ head_b, const float* __restrict__ qkv_w,
    const float* __restrict__ proj_w, const float* __restrict__ ffn_w1,
    const float* __restrict__ ffn_w2, const ushort* __restrict__ wf,
    float* __restrict__ out) {
  const int tid = threadIdx.x;
  const int lane = tid & 63;
  const int w = tid >> 6;
  const int li16 = lane & 15;
  const int lg = lane >> 4;

  __shared__ __align__(16) float hres[ROWS][HPAD];
  __shared__ __align__(16) ushort actA[ROWS][APAD];
  __shared__ __align__(16) ushort bufQ[ROWS][APAD];
  __shared__ __align__(16) ushort bufK[ROWS][APAD];
  __shared__ __align__(16) ushort sP[NB * 4 * 10 * 12];
  __shared__ __align__(16) float sX[NB * 40];
  __shared__ int sFlag;

  // -------- stage x: 320 elements, 256 threads -> two steps (v3 BUG: only 256 loaded)
  {
    const float* xb = x + (size_t)blockIdx.x * (NB * 40);
    sX[tid] = xb[tid];
    if (tid < NB * 40 - 256) sX[256 + tid] = xb[256 + tid];
    if (tid == 0) sFlag = 0;
  }
  __syncthreads();
  // -------- embed --------
#pragma unroll
  for (int it = 0; it < 20; ++it) {
    int task = tid + it * 256;
    int r = task >> 6, c = task & 63;
    int b = r & 7, t = r >> 3;
    float acc = embed_b[c];
    const float* xv = &sX[b * 40 + t * 4];
#pragma unroll
    for (int i = 0; i < 4; ++i) acc = fmaf(xv[i], embed_w[i * 64 + c], acc);
    hres[r][c] = acc;
  }
  __syncthreads();

  for (int li = 0; li < 3; ++li) {
    const ushort* qf = wf + li * 12288;
    const ushort* pf = wf + PROJF_OFF + li * 4096;
    const ushort* f1 = wf + F1F_OFF + li * 16384;
    const ushort* f2 = wf + F2F_OFF + li * 16384;

    ln_phase(hres, actA, &ln1_g[li * 64], &ln1_b[li * 64], tid);
    __syncthreads();

    // -------- Q,K GEMM --------
    {
      int4 bq[2][2];
#pragma unroll
      for (int ii = 0; ii < 2; ++ii) {
        int nt = w + 4 * ii;
#pragma unroll
        for (int kt = 0; kt < 2; ++kt)
          bq[ii][kt] = ((const int4*)qf)[(kt * 12 + nt) * 64 + lane];
      }
#pragma unroll
      for (int mt = 0; mt < MT; ++mt) {
        int arow = mt * 16 + li16;
        int4 a0 = *(const int4*)&actA[arow][lg * 8];
        int4 a1 = *(const int4*)&actA[arow][32 + lg * 8];
#pragma unroll
        for (int ii = 0; ii < 2; ++ii) {
          f32x4 acc = {0.f, 0.f, 0.f, 0.f};
          acc = mfma_bf16(a0, bq[ii][0], acc);
          acc = mfma_bf16(a1, bq[ii][1], acc);
          int nt = w + 4 * ii;
          ushort(*dst)[APAD] = (nt < 4) ? bufQ : bufK;
          int col = (nt & 3) * 16 + li16;
#pragma unroll
          for (int r = 0; r < 4; ++r) dst[mt * 16 + lg * 4 + r][col] = f2b(acc[r]);
        }
      }
    }
    __syncthreads();

    // -------- diagnostics (layer 0, block 0 only; reads only; sets sFlag bits)
    if (li == 0 && blockIdx.x == 0) {
      int f = 0;
      for (int idx = tid; idx < 12288; idx += 256) {        // bit0a: read-side qkv frag
        int kt = idx / 6144, rem = idx % 6144;
        int nt = rem / 512, l = (rem % 512) / 8, j = rem & 7;
        int k = kt * 32 + (l >> 4) * 8 + j, n = nt * 16 + (l & 15);
        if (qf[(kt * 12 + nt) * 512 + l * 8 + j] != f2b(qkv_w[k * 192 + n])) f |= 1;
      }
      for (int idx = tid; idx < WS_ELEMS; idx += 256) {     // bit0b: full ws integrity
        const float* src; int N, Ksz, lst, base;
        if (idx < PROJF_OFF) { src = qkv_w; N = 192; Ksz = 64; lst = 12288; base = idx; }
        else if (idx < F1F_OFF) { src = proj_w; N = 64; Ksz = 64; lst = 4096; base = idx - PROJF_OFF; }
        else if (idx < F2F_OFF) { src = ffn_w1; N = 256; Ksz = 64; lst = 16384; base = idx - F1F_OFF; }
        else { src = ffn_w2; N = 64; Ksz = 256; lst = 16384; base = idx - F2F_OFF; }
        int layer = base / lst, rem = base % lst;
        int ntk = N / 16;
        int kt = rem / (ntk * 512); rem %= (ntk * 512);
        int nt = rem / 512, l = (rem % 512) / 8, j = rem & 7;
        int k = kt * 32 + (l >> 4) * 8 + j, n = nt * 16 + (l & 15);
        if (wf[idx] != f2b(src[(size_t)layer * Ksz * N + (size_t)k * N + n])) f |= 1;
      }
      for (int task = tid; task < 80 * 128; task += 256) {  // bit1: QKV GEMM vs VALU
        int r = task >> 7, c = task & 127;
        float e = 0.f;
        for (int k = 0; k < 64; ++k)
          e = fmaf(b2f(actA[r][k]), b2f(f2b(qkv_w[k * 192 + c])), e);
        float act = b2f((c < 64) ? bufQ[r][c] : bufK[r][c - 64]);
        if (fabsf(e - act) > 0.05f) f |= 2;
      }
      for (int task = tid; task < 80 * 64; task += 256) {   // bit2: embed/x-staging
        int r = task >> 6, c = task & 63;
        float e = embed_b[c];
        for (int i = 0; i < 4; ++i)
          e = fmaf(x[(r & 7) * 40 + (r >> 3) * 4 + i], embed_w[i * 64 + c], e);
        if (fabsf(hres[r][c] - e) > 1e-3f) f |= 4;
      }
      for (int task = tid; task < 80 * 128; task += 256) {  // bit3: LN1+GEMM chain
        int r = task >> 7, c = task & 127;
        float s = 0.f, s2 = 0.f;
        for (int i = 0; i < 64; ++i) { float v = hres[r][i]; s += v; s2 = fmaf(v, v, s2); }
        float m = s * 0.015625f, rstd = rsqrtf(s2 * 0.015625f - m * m + 1e-5f);
        float e = 0.f;
        for (int k = 0; k < 64; ++k) {
          float z = b2f(f2b((hres[r][k] - m) * rstd * ln1_g[k] + ln1_b[k]));
          e = fmaf(z, b2f(f2b(qkv_w[k * 192 + c])), e);
        }
        float act = b2f((c < 64) ? bufQ[r][c] : bufK[r][c - 64]);
        if (fabsf(e - act) > 0.05f) f |= 8;
      }
      if (f) atomicOr(&sFlag, f);
    }

    // -------- scores + softmax --------
    {
      auto do_score = [&](int p) {
        int qt = 2 * p + (lane >> 5);
        int b = lane & 7, h = (lane >> 3) & 3;
        float qv[16];
        {
          int4 qa = *(const int4*)&bufQ[qt * 8 + b][h * 16];
          int4 qb = *(const int4*)&bufQ[qt * 8 + b][h * 16 + 8];
          unpack8(qa, qv); unpack8(qb, qv + 8);
        }
        float sc[10], mx = -1e30f;
#pragma unroll
        for (int kt = 0; kt < 10; ++kt) {
          int4 ka = *(const int4*)&bufK[kt * 8 + b][h * 16];
          int4 kb = *(const int4*)&bufK[kt * 8 + b][h * 16 + 8];
          float kv[16]; unpack8(ka, kv); unpack8(kb, kv + 8);
          float d = 0.f;
#pragma unroll
          for (int i = 0; i < 16; ++i) d = fmaf(qv[i], kv[i], d);
          sc[kt] = (kt <= qt) ? d * 0.25f : -1e30f;
          mx = fmaxf(mx, sc[kt]);
        }
        float ssum = 0.f;
#pragma unroll
        for (int kt = 0; kt < 10; ++kt) { sc[kt] = __expf(sc[kt] - mx); ssum += sc[kt]; }
        float inv = __builtin_amdgcn_rcpf(ssum);
        ushort* prow = &sP[((b * 4 + h) * 10 + qt) * 12];
#pragma unroll
        for (int kt = 0; kt < 10; ++kt) prow[kt] = f2b(sc[kt] * inv);
      };
      if (w < 3) do_score(4 - w);
      if (w == 1) do_score(0);
      if (w == 2) do_score(1);
    }
    __syncthreads();

    // -------- V GEMM --------
    {
      int nt = 8 + w;
      int4 b0 = ((const int4*)qf)[(0 * 12 + nt) * 64 + lane];
      int4 b1 = ((const int4*)qf)[(1 * 12 + nt) * 64 + lane];
#pragma unroll
      for (int mt = 0; mt < MT; ++mt) {
        int arow = mt * 16 + li16;
        int4 a0 = *(const int4*)&actA[arow][lg * 8];
        int4 a1 = *(const int4*)&actA[arow][32 + lg * 8];
        f32x4 acc = {0.f, 0.f, 0.f, 0.f};
        acc = mfma_bf16(a0, b0, acc);
        acc = mfma_bf16(a1, b1, acc);
        int col = w * 16 + li16;
#pragma unroll
        for (int r = 0; r < 4; ++r) bufQ[mt * 16 + lg * 4 + r][col] = f2b(acc[r]);
      }
    }
    __syncthreads();

    // -------- AV --------
#pragma unroll
    for (int it = 0; it < 20; ++it) {
      int task = tid + it * 256;
      int r = task >> 6, ch = task & 63;
      int b = r & 7, qt = r >> 3, h = ch >> 4;
      const ushort* prow = &sP[((b * 4 + h) * 10 + qt) * 12];
      float acc = 0.f;
      for (int kt = 0; kt <= qt; ++kt)
        acc = fmaf(b2f(prow[kt]), b2f(bufQ[kt * 8 + b][ch]), acc);
      actA[r][ch] = f2b(acc);
    }
    __syncthreads();

    // -------- proj + residual --------
    {
      int4 b0 = ((const int4*)pf)[(0 * 4 + w) * 64 + lane];
      int4 b1 = ((const int4*)pf)[(1 * 4 + w) * 64 + lane];
      int col = w * 16 + li16;
#pragma unroll
      for (int mt = 0; mt < MT; ++mt) {
        int arow = mt * 16 + li16;
        int4 a0 = *(const int4*)&actA[arow][lg * 8];
        int4 a1 = *(const int4*)&actA[arow][32 + lg * 8];
        f32x4 acc = {0.f, 0.f, 0.f, 0.f};
        acc = mfma_bf16(a0, b0, acc);
        acc = mfma_bf16(a1, b1, acc);
#pragma unroll
        for (int r = 0; r < 4; ++r) hres[mt * 16 + lg * 4 + r][col] += acc[r];
      }
    }
    __syncthreads();

    ln_phase(hres, actA, &ln2_g[li * 64], &ln2_b[li * 64], tid);
    __syncthreads();

    // -------- fused FFN --------
    {
      f32x4 acc2[MT];
#pragma unroll
      for (int mt = 0; mt < MT; ++mt) acc2[mt] = {0.f, 0.f, 0.f, 0.f};
#pragma unroll
      for (int c = 0; c < 4; ++c) {
        int nt1 = c * 4 + w;
        int4 b0 = ((const int4*)f1)[(0 * 16 + nt1) * 64 + lane];
        int4 b1 = ((const int4*)f1)[(1 * 16 + nt1) * 64 + lane];
        float bias1 = ffn_b1[li * 256 + c * 64 + w * 16 + li16];
#pragma unroll
        for (int mt = 0; mt < MT; ++mt) {
          int arow = mt * 16 + li16;
          int4 a0 = *(const int4*)&actA[arow][lg * 8];
          int4 a1 = *(const int4*)&actA[arow][32 + lg * 8];
          f32x4 acc = {0.f, 0.f, 0.f, 0.f};
          acc = mfma_bf16(a0, b0, acc);
          acc = mfma_bf16(a1, b1, acc);
#pragma unroll
          for (int r = 0; r < 4; ++r)
            bufK[mt * 16 + lg * 4 + r][w * 16 + li16] = f2b(gelu_f(acc[r] + bias1));
        }
        __syncthreads();
        int4 c0 = ((const int4*)f2)[((c * 2 + 0) * 4 + w) * 64 + lane];
        int4 c1 = ((const int4*)f2)[((c * 2 + 1) * 4 + w) * 64 + lane];
#pragma unroll
        for (int mt = 0; mt < MT; ++mt) {
          int arow = mt * 16 + li16;
          int4 a0 = *(const int4*)&bufK[arow][lg * 8];
          int4 a1 = *(const int4*)&bufK[arow][32 + lg * 8];
          acc2[mt] = mfma_bf16(a0, c0, acc2[mt]);
          acc2[mt] = mfma_bf16(a1, c1, acc2[mt]);
        }
        __syncthreads();
      }
      float bias2 = ffn_b2[li * 64 + w * 16 + li16];
      int col = w * 16 + li16;
#pragma unroll
      for (int mt = 0; mt < MT; ++mt)
#pragma unroll
        for (int r = 0; r < 4; ++r) hres[mt * 16 + lg * 4 + r][col] += acc2[mt][r] + bias2;
    }
    __syncthreads();
  }

  // -------- final LN + head --------
  if (tid < NB) {
    const float* row = hres[72 + tid];
    float s = 0.f, s2 = 0.f;
#pragma unroll
    for (int i = 0; i < 64; ++i) { float v = row[i]; s += v; s2 = fmaf(v, v, s2); }
    float m = s * 0.015625f;
    sX[tid * 2] = m;
    sX[tid * 2 + 1] = rsqrtf(s2 * 0.015625f - m * m + 1e-5f);
  }
  __syncthreads();
  if (tid < NB * 10) {
    int b = tid / 10, j = tid % 10;
    float m = sX[b * 2], rstd = sX[b * 2 + 1];
    float acc = head_b[j];
    const float* row = hres[72 + b];
#pragma unroll
    for (int d = 0; d < 64; ++d) {
      float z = (row[d] - m) * rstd * lnf_g[d] + lnf_b[d];
      acc = fmaf(z, head_w[d * 10 + j], acc);
    }
    out[((size_t)blockIdx.x * NB + b) * 10 + j] = acc;
  }
  __syncthreads();
  if (blockIdx.x == 0 && tid == 0) out[0] += 1024.f * (float)sFlag;  // diag signature
}

}  // namespace

extern "C" void kernel_launch(void* const* d_in, const int* in_sizes, int n_in,
                              void* d_out, int out_size, void* d_ws, size_t ws_size,
                              hipStream_t stream) {
  const float* x       = (const float*)d_in[0];
  const float* embed_w = (const float*)d_in[1];
  const float* embed_b = (const float*)d_in[2];
  const float* ln1_g   = (const float*)d_in[3];
  const float* ln1_b   = (const float*)d_in[4];
  const float* qkv_w   = (const float*)d_in[5];
  const float* proj_w  = (const float*)d_in[6];
  const float* ln2_g   = (const float*)d_in[7];
  const float* ln2_b   = (const float*)d_in[8];
  const float* ffn_w1  = (const float*)d_in[9];
  const float* ffn_b1  = (const float*)d_in[10];
  const float* ffn_w2  = (const float*)d_in[11];
  const float* ffn_b2  = (const float*)d_in[12];
  const float* lnf_g   = (const float*)d_in[13];
  const float* lnf_b   = (const float*)d_in[14];
  const float* head_w  = (const float*)d_in[15];
  const float* head_b  = (const float*)d_in[16];
  ushort* wf = (ushort*)d_ws;
  float* out = (float*)d_out;

  prep_weights<<<dim3((WS_ELEMS + 255) / 256), dim3(256), 0, stream>>>(
      qkv_w, proj_w, ffn_w1, ffn_w2, wf);
  wtf_mfma<<<dim3(NBLK), dim3(256), 0, stream>>>(
      x, embed_w, embed_b, ln1_g, ln1_b, ln2_g, ln2_b, ffn_b1, ffn_b2,
      lnf_g, lnf_b, head_w, head_b, qkv_w, proj_w, ffn_w1, ffn_w2, wf, out);
}

// Round 5
// 375.909 us; speedup vs baseline: 3.5846x; 1.5539x over previous
//
#include <hip/hip_runtime.h>

namespace {

typedef __bf16 bf16x8 __attribute__((ext_vector_type(8)));
typedef float f32x4 __attribute__((ext_vector_type(4)));

constexpr int NB = 8;          // batches per block
constexpr int ROWS = 80;       // NB * T   (row = t*8 + b)
constexpr int MT = 5;          // M-tiles of 16 rows
constexpr int APAD = 72;       // bf16 staging row pitch (144 B)
constexpr int NBLK = 16384 / NB;
constexpr float EPS = 1e-5f;

// ws bf16-fragment offsets (ushort elements)
constexpr int PROJF_OFF = 36864;
constexpr int F1F_OFF = 49152;
constexpr int F2F_OFF = 98304;
constexpr int WS_ELEMS = 147456;

// LDS arena offsets (bytes)
constexpr int ACT_OFF = 0;           // ushort[80][72]           11520
constexpr int BUFQ_OFF = 11520;      // ushort[80][72]           11520  (also hscr f32[80][66])
constexpr int BUFK_OFF = 23040;      // ushort[80][72]           11520
constexpr int SPR_OFF = 34560;       // sP / sX / sPart / sGB     7680
constexpr int ARENA_BYTES = 42240;

__device__ __forceinline__ ushort f2b(float f) {  // RNE f32->bf16
  uint u = __float_as_uint(f);
  return (ushort)((u + 0x7fffu + ((u >> 16) & 1u)) >> 16);
}
__device__ __forceinline__ float b2f(ushort s) {
  return __uint_as_float((uint)s << 16);
}
__device__ __forceinline__ void unpack8(int4 v, float* f) {
  uint u;
  u = (uint)v.x; f[0] = __uint_as_float(u << 16); f[1] = __uint_as_float(u & 0xffff0000u);
  u = (uint)v.y; f[2] = __uint_as_float(u << 16); f[3] = __uint_as_float(u & 0xffff0000u);
  u = (uint)v.z; f[4] = __uint_as_float(u << 16); f[5] = __uint_as_float(u & 0xffff0000u);
  u = (uint)v.w; f[6] = __uint_as_float(u << 16); f[7] = __uint_as_float(u & 0xffff0000u);
}
__device__ __forceinline__ float gelu_f(float v) {  // 0.5v(1+erf(v/sqrt2))
  float ax = fabsf(v) * 0.70710678118f;
  float t = __builtin_amdgcn_rcpf(fmaf(0.3275911f, ax, 1.0f));
  float poly = t * fmaf(t, fmaf(t, fmaf(t, fmaf(t, 1.061405429f, -1.453152027f),
                                        1.421413741f), -0.284496736f), 0.254829592f);
  float erfv = fmaf(-poly, __expf(-ax * ax), 1.0f);
  erfv = copysignf(erfv, v);
  return 0.5f * v * (1.0f + erfv);
}
__device__ __forceinline__ f32x4 mfma_bf16(int4 a, int4 b, f32x4 c) {
  return __builtin_amdgcn_mfma_f32_16x16x32_bf16(
      __builtin_bit_cast(bf16x8, a), __builtin_bit_cast(bf16x8, b), c, 0, 0, 0);
}

// ---------------- weight prep: fp32 row-major -> bf16 B-fragment layout ----
__global__ __launch_bounds__(256) void prep_weights(
    const float* __restrict__ qkv_w, const float* __restrict__ proj_w,
    const float* __restrict__ ffn_w1, const float* __restrict__ ffn_w2,
    ushort* __restrict__ ws) {
  int idx = blockIdx.x * 256 + threadIdx.x;
  if (idx >= WS_ELEMS) return;
  const float* src;
  int N, Ksz, lstride, base;
  if (idx < PROJF_OFF) { src = qkv_w; N = 192; Ksz = 64; lstride = 12288; base = idx; }
  else if (idx < F1F_OFF) { src = proj_w; N = 64; Ksz = 64; lstride = 4096; base = idx - PROJF_OFF; }
  else if (idx < F2F_OFF) { src = ffn_w1; N = 256; Ksz = 64; lstride = 16384; base = idx - F1F_OFF; }
  else { src = ffn_w2; N = 64; Ksz = 256; lstride = 16384; base = idx - F2F_OFF; }
  int layer = base / lstride, rem = base % lstride;
  int ntk = N / 16;
  int kt = rem / (ntk * 512); rem %= (ntk * 512);
  int nt = rem / 512;
  int lane = (rem % 512) / 8, j = rem % 8;
  int k = kt * 32 + (lane >> 4) * 8 + j;
  int n = nt * 16 + (lane & 15);
  ws[idx] = f2b(src[(size_t)layer * Ksz * N + (size_t)k * N + n]);
}

__global__ __launch_bounds__(256, 3) void wtf_mfma(
    const float* __restrict__ x, const float* __restrict__ embed_w,
    const float* __restrict__ embed_b, const float* __restrict__ ln1_g,
    const float* __restrict__ ln1_b, const float* __restrict__ ln2_g,
    const float* __restrict__ ln2_b, const float* __restrict__ ffn_b1,
    const float* __restrict__ ffn_b2, const float* __restrict__ lnf_g,
    const float* __restrict__ lnf_b, const float* __restrict__ head_w,
    const float* __restrict__ head_b, const ushort* __restrict__ wf,
    float* __restrict__ out) {
  const int tid = threadIdx.x;
  const int lane = tid & 63;
  const int w = tid >> 6;
  const int li16 = lane & 15;
  const int lg = lane >> 4;
  const int col = w * 16 + li16;  // this thread's owned output column

  __shared__ __align__(16) char lds_arena[ARENA_BYTES];
  ushort(*actA)[APAD] = (ushort(*)[APAD])(lds_arena + ACT_OFF);
  ushort(*bufQ)[APAD] = (ushort(*)[APAD])(lds_arena + BUFQ_OFF);
  ushort(*bufK)[APAD] = (ushort(*)[APAD])(lds_arena + BUFK_OFF);
  float(*hscr)[66]    = (float(*)[66])(lds_arena + BUFQ_OFF);   // aliases bufQ+bufK
  ushort* sP          = (ushort*)(lds_arena + SPR_OFF);          // [b][h][qt]*12+kt
  float* sXf          = (float*)(lds_arena + SPR_OFF);           // 320 f32 (embed only)
  float2(*sPart)[3]   = (float2(*)[3])(lds_arena + SPR_OFF);     // 80x3 f32x2 (LN only)
  float* sGB          = (float*)(lds_arena + SPR_OFF + 2048);    // 128 f32 g|b (LN only)

  // residual in registers: h[mt][r] = h(row=mt*16+lg*4+r, col)
  f32x4 h[MT];

  // -------- LayerNorm on register-h (3 syncs) --------
  auto ln_reg = [&](const float* g, const float* b) {
    // s1: dump h -> hscr; stage g,b
#pragma unroll
    for (int mt = 0; mt < MT; ++mt)
#pragma unroll
      for (int r = 0; r < 4; ++r) hscr[mt * 16 + lg * 4 + r][col] = h[mt][r];
    if (tid < 64) { sGB[tid] = g[tid]; sGB[64 + tid] = b[tid]; }
    __syncthreads();
    // s2: per-(row,chunk) partial sums; 240 active threads
    const int row = tid % 80;
    const int c3 = tid / 80;
    const int beg = (c3 == 0) ? 0 : (c3 == 1) ? 22 : 44;
    const int len2 = (c3 < 2) ? 11 : 10;
    if (tid < 240) {
      float s = 0.f, s2 = 0.f;
      for (int k = 0; k < len2; ++k) {
        float2 v = *(const float2*)&hscr[row][beg + 2 * k];
        s += v.x + v.y;
        s2 = fmaf(v.x, v.x, fmaf(v.y, v.y, s2));
      }
      sPart[row][c3] = make_float2(s, s2);
    }
    __syncthreads();
    // s3: combine stats, normalize, pack bf16 -> actA
    if (tid < 240) {
      float2 p0 = sPart[row][0], p1 = sPart[row][1], p2 = sPart[row][2];
      float s = p0.x + p1.x + p2.x, s2 = p0.y + p1.y + p2.y;
      float m = s * 0.015625f;
      float rstd = rsqrtf(s2 * 0.015625f - m * m + EPS);
      for (int k = 0; k < len2; ++k) {
        int c = beg + 2 * k;
        float2 v = *(const float2*)&hscr[row][c];
        float v0 = (v.x - m) * rstd * sGB[c] + sGB[64 + c];
        float v1 = (v.y - m) * rstd * sGB[c + 1] + sGB[64 + c + 1];
        *(uint*)&actA[row][c] = (uint)f2b(v0) | ((uint)f2b(v1) << 16);
      }
    }
    __syncthreads();
  };

  // -------- stage x (320 elems, two steps) + embed into registers --------
  {
    const float* xb = x + (size_t)blockIdx.x * (NB * 40);
    sXf[tid] = xb[tid];
    if (tid < NB * 40 - 256) sXf[256 + tid] = xb[256 + tid];
  }
  __syncthreads();
  {
    float ew0 = embed_w[col], ew1 = embed_w[64 + col];
    float ew2 = embed_w[128 + col], ew3 = embed_w[192 + col];
    float eb = embed_b[col];
#pragma unroll
    for (int mt = 0; mt < MT; ++mt)
#pragma unroll
      for (int r = 0; r < 4; ++r) {
        int row = mt * 16 + lg * 4 + r;
        const float* xv = &sXf[(row & 7) * 40 + (row >> 3) * 4];
        float acc = eb;
        acc = fmaf(xv[0], ew0, acc);
        acc = fmaf(xv[1], ew1, acc);
        acc = fmaf(xv[2], ew2, acc);
        acc = fmaf(xv[3], ew3, acc);
        h[mt][r] = acc;
      }
  }
  __syncthreads();  // sXf reads done before LN1 reuses the region

  for (int li = 0; li < 3; ++li) {
    const ushort* qf = wf + li * 12288;
    const ushort* pf = wf + PROJF_OFF + li * 4096;
    const ushort* f1 = wf + F1F_OFF + li * 16384;
    const ushort* f2 = wf + F2F_OFF + li * 16384;

    // -------- LN1 --------
    ln_reg(&ln1_g[li * 64], &ln1_b[li * 64]);

    // -------- Q,K GEMM (nt 0..7) -> bufQ, bufK --------
    {
      int4 bq[2][2];
#pragma unroll
      for (int ii = 0; ii < 2; ++ii) {
        int nt = w + 4 * ii;
#pragma unroll
        for (int kt = 0; kt < 2; ++kt)
          bq[ii][kt] = ((const int4*)qf)[(kt * 12 + nt) * 64 + lane];
      }
#pragma unroll
      for (int mt = 0; mt < MT; ++mt) {
        int arow = mt * 16 + li16;
        int4 a0 = *(const int4*)&actA[arow][lg * 8];
        int4 a1 = *(const int4*)&actA[arow][32 + lg * 8];
#pragma unroll
        for (int ii = 0; ii < 2; ++ii) {
          f32x4 acc = {0.f, 0.f, 0.f, 0.f};
          acc = mfma_bf16(a0, bq[ii][0], acc);
          acc = mfma_bf16(a1, bq[ii][1], acc);
          int nt = w + 4 * ii;
          ushort(*dst)[APAD] = (nt < 4) ? bufQ : bufK;
          int dcol = (nt & 3) * 16 + li16;
#pragma unroll
          for (int r = 0; r < 4; ++r) dst[mt * 16 + lg * 4 + r][dcol] = f2b(acc[r]);
        }
      }
    }
    __syncthreads();

    // -------- scores + softmax (balanced 2/1/1/1 over qt-pairs) --------
    {
      auto do_score = [&](int p) {
        int qt = 2 * p + (lane >> 5);
        int b = lane & 7, hh = (lane >> 3) & 3;
        float qv[16];
        {
          int4 qa = *(const int4*)&bufQ[qt * 8 + b][hh * 16];
          int4 qb = *(const int4*)&bufQ[qt * 8 + b][hh * 16 + 8];
          unpack8(qa, qv); unpack8(qb, qv + 8);
        }
        float sc[10], mx = -1e30f;
#pragma unroll
        for (int kt = 0; kt < 10; ++kt) {
          int4 ka = *(const int4*)&bufK[kt * 8 + b][hh * 16];
          int4 kb = *(const int4*)&bufK[kt * 8 + b][hh * 16 + 8];
          float kv[16]; unpack8(ka, kv); unpack8(kb, kv + 8);
          float d = 0.f;
#pragma unroll
          for (int i = 0; i < 16; ++i) d = fmaf(qv[i], kv[i], d);
          sc[kt] = (kt <= qt) ? d * 0.25f : -1e30f;
          mx = fmaxf(mx, sc[kt]);
        }
        float ssum = 0.f;
#pragma unroll
        for (int kt = 0; kt < 10; ++kt) { sc[kt] = __expf(sc[kt] - mx); ssum += sc[kt]; }
        float inv = __builtin_amdgcn_rcpf(ssum);
        ushort* prow = &sP[((b * 4 + hh) * 10 + qt) * 12];
#pragma unroll
        for (int kt = 0; kt < 10; ++kt) prow[kt] = f2b(sc[kt] * inv);
      };
      if (w == 0) { do_score(0); do_score(4); }
      else do_score(w);
    }
    __syncthreads();

    // -------- V GEMM (nt 8..11) -> bufQ --------
    {
      int nt = 8 + w;
      int4 b0 = ((const int4*)qf)[(0 * 12 + nt) * 64 + lane];
      int4 b1 = ((const int4*)qf)[(1 * 12 + nt) * 64 + lane];
#pragma unroll
      for (int mt = 0; mt < MT; ++mt) {
        int arow = mt * 16 + li16;
        int4 a0 = *(const int4*)&actA[arow][lg * 8];
        int4 a1 = *(const int4*)&actA[arow][32 + lg * 8];
        f32x4 acc = {0.f, 0.f, 0.f, 0.f};
        acc = mfma_bf16(a0, b0, acc);
        acc = mfma_bf16(a1, b1, acc);
#pragma unroll
        for (int r = 0; r < 4; ++r) bufQ[mt * 16 + lg * 4 + r][col] = f2b(acc[r]);
      }
    }
    __syncthreads();

    // -------- AV (VALU): y = P @ V -> actA --------
#pragma unroll
    for (int it = 0; it < 20; ++it) {
      int task = tid + it * 256;
      int r = task >> 6, ch = task & 63;
      int b = r & 7, qt = r >> 3, hh = ch >> 4;
      const ushort* prow = &sP[((b * 4 + hh) * 10 + qt) * 12];
      float acc = 0.f;
      for (int kt = 0; kt <= qt; ++kt)
        acc = fmaf(b2f(prow[kt]), b2f(bufQ[kt * 8 + b][ch]), acc);
      actA[r][ch] = f2b(acc);
    }
    __syncthreads();

    // -------- proj + residual (into registers) --------
    {
      int4 b0 = ((const int4*)pf)[(0 * 4 + w) * 64 + lane];
      int4 b1 = ((const int4*)pf)[(1 * 4 + w) * 64 + lane];
#pragma unroll
      for (int mt = 0; mt < MT; ++mt) {
        int arow = mt * 16 + li16;
        int4 a0 = *(const int4*)&actA[arow][lg * 8];
        int4 a1 = *(const int4*)&actA[arow][32 + lg * 8];
        f32x4 acc = {0.f, 0.f, 0.f, 0.f};
        acc = mfma_bf16(a0, b0, acc);
        acc = mfma_bf16(a1, b1, acc);
#pragma unroll
        for (int r = 0; r < 4; ++r) h[mt][r] += acc[r];
      }
    }
    // no sync: LN2 s1 touches only hscr (bufQ/K region; last read at AV, covered)

    // -------- LN2 --------
    ln_reg(&ln2_g[li * 64], &ln2_b[li * 64]);

    // -------- fused FFN: 2 chunk-pairs, 2 syncs each --------
    {
#pragma unroll
      for (int cp = 0; cp < 2; ++cp) {
#pragma unroll
        for (int cc = 0; cc < 2; ++cc) {
          int c = cp * 2 + cc;
          int nt1 = c * 4 + w;
          int4 b0 = ((const int4*)f1)[(0 * 16 + nt1) * 64 + lane];
          int4 b1 = ((const int4*)f1)[(1 * 16 + nt1) * 64 + lane];
          float bias1 = ffn_b1[li * 256 + c * 64 + col];
          ushort(*gbuf)[APAD] = cc ? bufK : bufQ;
#pragma unroll
          for (int mt = 0; mt < MT; ++mt) {
            int arow = mt * 16 + li16;
            int4 a0 = *(const int4*)&actA[arow][lg * 8];
            int4 a1 = *(const int4*)&actA[arow][32 + lg * 8];
            f32x4 acc = {0.f, 0.f, 0.f, 0.f};
            acc = mfma_bf16(a0, b0, acc);
            acc = mfma_bf16(a1, b1, acc);
#pragma unroll
            for (int r = 0; r < 4; ++r)
              gbuf[mt * 16 + lg * 4 + r][col] = f2b(gelu_f(acc[r] + bias1));
          }
        }
        __syncthreads();
        f32x4 acc2[MT];
#pragma unroll
        for (int mt = 0; mt < MT; ++mt) acc2[mt] = {0.f, 0.f, 0.f, 0.f};
#pragma unroll
        for (int cc = 0; cc < 2; ++cc) {
          int c = cp * 2 + cc;
          int4 c0 = ((const int4*)f2)[((c * 2 + 0) * 4 + w) * 64 + lane];
          int4 c1 = ((const int4*)f2)[((c * 2 + 1) * 4 + w) * 64 + lane];
          ushort(*gbuf)[APAD] = cc ? bufK : bufQ;
#pragma unroll
          for (int mt = 0; mt < MT; ++mt) {
            int arow = mt * 16 + li16;
            int4 a0 = *(const int4*)&gbuf[arow][lg * 8];
            int4 a1 = *(const int4*)&gbuf[arow][32 + lg * 8];
            acc2[mt] = mfma_bf16(a0, c0, acc2[mt]);
            acc2[mt] = mfma_bf16(a1, c1, acc2[mt]);
          }
        }
#pragma unroll
        for (int mt = 0; mt < MT; ++mt)
#pragma unroll
          for (int r = 0; r < 4; ++r) h[mt][r] += acc2[mt][r];
        __syncthreads();
      }
      float bias2 = ffn_b2[li * 64 + col];
#pragma unroll
      for (int mt = 0; mt < MT; ++mt)
#pragma unroll
        for (int r = 0; r < 4; ++r) h[mt][r] += bias2;
    }
  }

  // -------- final LN (rows 72..79) + head --------
  if (lg >= 2) {
#pragma unroll
    for (int r = 0; r < 4; ++r) hscr[(lg - 2) * 4 + r][col] = h[4][r];
  }
  __syncthreads();
  float2* sFin = (float2*)(lds_arena + SPR_OFF);
  if (tid < 8) {
    float s = 0.f, s2 = 0.f;
#pragma unroll
    for (int i = 0; i < 64; ++i) { float v = hscr[tid][i]; s += v; s2 = fmaf(v, v, s2); }
    float m = s * 0.015625f;
    sFin[tid] = make_float2(m, rsqrtf(s2 * 0.015625f - m * m + EPS));
  }
  __syncthreads();
  if (tid < 80) {
    int b = tid / 10, j = tid % 10;
    float m = sFin[b].x, rstd = sFin[b].y;
    float acc = head_b[j];
#pragma unroll
    for (int d = 0; d < 64; ++d) {
      float z = (hscr[b][d] - m) * rstd * lnf_g[d] + lnf_b[d];
      acc = fmaf(z, head_w[d * 10 + j], acc);
    }
    out[((size_t)blockIdx.x * NB + b) * 10 + j] = acc;
  }
}

}  // namespace

extern "C" void kernel_launch(void* const* d_in, const int* in_sizes, int n_in,
                              void* d_out, int out_size, void* d_ws, size_t ws_size,
                              hipStream_t stream) {
  const float* x       = (const float*)d_in[0];
  const float* embed_w = (const float*)d_in[1];
  const float* embed_b = (const float*)d_in[2];
  const float* ln1_g   = (const float*)d_in[3];
  const float* ln1_b   = (const float*)d_in[4];
  const float* qkv_w   = (const float*)d_in[5];
  const float* proj_w  = (const float*)d_in[6];
  const float* ln2_g   = (const float*)d_in[7];
  const float* ln2_b   = (const float*)d_in[8];
  const float* ffn_w1  = (const float*)d_in[9];
  const float* ffn_b1  = (const float*)d_in[10];
  const float* ffn_w2  = (const float*)d_in[11];
  const float* ffn_b2  = (const float*)d_in[12];
  const float* lnf_g   = (const float*)d_in[13];
  const float* lnf_b   = (const float*)d_in[14];
  const float* head_w  = (const float*)d_in[15];
  const float* head_b  = (const float*)d_in[16];
  ushort* wf = (ushort*)d_ws;
  float* out = (float*)d_out;

  prep_weights<<<dim3((WS_ELEMS + 255) / 256), dim3(256), 0, stream>>>(
      qkv_w, proj_w, ffn_w1, ffn_w2, wf);
  wtf_mfma<<<dim3(NBLK), dim3(256), 0, stream>>>(
      x, embed_w, embed_b, ln1_g, ln1_b, ln2_g, ln2_b, ffn_b1, ffn_b2,
      lnf_g, lnf_b, head_w, head_b, wf, out);
}

// Round 6
// 272.313 us; speedup vs baseline: 4.9483x; 1.3804x over previous
//
#include <hip/hip_runtime.h>

namespace {

typedef __bf16 bf16x8 __attribute__((ext_vector_type(8)));
typedef float f32x4 __attribute__((ext_vector_type(4)));

constexpr int NB = 8;          // batches per block
constexpr int ROWS = 80;       // NB * T   (row = t*8 + b)
constexpr int MT = 5;          // M-tiles of 16 rows
constexpr int APAD = 72;       // bf16 staging row pitch (144 B)
constexpr int TPITCH = 82;     // bufT (V^T) pitch: 164 B -> bank stride 41 (odd/2) = conflict-free
constexpr int NBLK = 16384 / NB;
constexpr float EPS = 1e-5f;

// ws bf16-fragment offsets (ushort elements)
constexpr int PROJF_OFF = 36864;
constexpr int F1F_OFF = 49152;
constexpr int F2F_OFF = 98304;
constexpr int WS_ELEMS = 147456;

// LDS arena offsets (bytes)
constexpr int ACT_OFF = 0;           // bf16[80][72] 11520   (aliased: bufT bf16[64][82]=10496)
constexpr int BUFQ_OFF = 11520;      // bf16[80][72] 11520   (aliased: hscr f32[80][66] spans Q+K)
constexpr int BUFK_OFF = 23040;      // bf16[80][72] 11520   (also y destination)
constexpr int SPR_OFF = 34560;       // 6400 B: sP bf16[3200] | sXf f32[320] | sPart+sGB
constexpr int ARENA_BYTES = 40960;   // = 160 KiB / 4  -> 4 blocks/CU

__device__ __forceinline__ uint pk2(float lo, float hi) {  // -> v_cvt_pk_bf16_f32
  ushort ul = __builtin_bit_cast(ushort, (__bf16)lo);
  ushort uh = __builtin_bit_cast(ushort, (__bf16)hi);
  return (uint)ul | ((uint)uh << 16);
}
__device__ __forceinline__ void unpack8(int4 v, float* f) {
  uint u;
  u = (uint)v.x; f[0] = __uint_as_float(u << 16); f[1] = __uint_as_float(u & 0xffff0000u);
  u = (uint)v.y; f[2] = __uint_as_float(u << 16); f[3] = __uint_as_float(u & 0xffff0000u);
  u = (uint)v.z; f[4] = __uint_as_float(u << 16); f[5] = __uint_as_float(u & 0xffff0000u);
  u = (uint)v.w; f[6] = __uint_as_float(u << 16); f[7] = __uint_as_float(u & 0xffff0000u);
}
__device__ __forceinline__ float gelu_f(float v) {  // 0.5v(1+erf(v/sqrt2)), A&S 7.1.26
  float ax = fabsf(v) * 0.70710678118f;
  float t = __builtin_amdgcn_rcpf(fmaf(0.3275911f, ax, 1.0f));
  float poly = t * fmaf(t, fmaf(t, fmaf(t, fmaf(t, 1.061405429f, -1.453152027f),
                                        1.421413741f), -0.284496736f), 0.254829592f);
  float erfv = fmaf(-poly, __expf(-ax * ax), 1.0f);
  erfv = copysignf(erfv, v);
  return 0.5f * v * (1.0f + erfv);
}
__device__ __forceinline__ f32x4 mfma_bf16(int4 a, int4 b, f32x4 c) {
  return __builtin_amdgcn_mfma_f32_16x16x32_bf16(
      __builtin_bit_cast(bf16x8, a), __builtin_bit_cast(bf16x8, b), c, 0, 0, 0);
}

// ---------------- weight prep: fp32 row-major -> bf16 B-fragment layout ----
__global__ __launch_bounds__(256) void prep_weights(
    const float* __restrict__ qkv_w, const float* __restrict__ proj_w,
    const float* __restrict__ ffn_w1, const float* __restrict__ ffn_w2,
    __bf16* __restrict__ ws) {
  int idx = blockIdx.x * 256 + threadIdx.x;
  if (idx >= WS_ELEMS) return;
  const float* src;
  int N, Ksz, lstride, base;
  if (idx < PROJF_OFF) { src = qkv_w; N = 192; Ksz = 64; lstride = 12288; base = idx; }
  else if (idx < F1F_OFF) { src = proj_w; N = 64; Ksz = 64; lstride = 4096; base = idx - PROJF_OFF; }
  else if (idx < F2F_OFF) { src = ffn_w1; N = 256; Ksz = 64; lstride = 16384; base = idx - F1F_OFF; }
  else { src = ffn_w2; N = 64; Ksz = 256; lstride = 16384; base = idx - F2F_OFF; }
  int layer = base / lstride, rem = base % lstride;
  int ntk = N / 16;
  int kt = rem / (ntk * 512); rem %= (ntk * 512);
  int nt = rem / 512;
  int lane = (rem % 512) / 8, j = rem % 8;
  int k = kt * 32 + (lane >> 4) * 8 + j;
  int n = nt * 16 + (lane & 15);
  ws[idx] = (__bf16)src[(size_t)layer * Ksz * N + (size_t)k * N + n];
}

__global__ __launch_bounds__(256, 4) void wtf_mfma(
    const float* __restrict__ x, const float* __restrict__ embed_w,
    const float* __restrict__ embed_b, const float* __restrict__ ln1_g,
    const float* __restrict__ ln1_b, const float* __restrict__ ln2_g,
    const float* __restrict__ ln2_b, const float* __restrict__ ffn_b1,
    const float* __restrict__ ffn_b2, const float* __restrict__ lnf_g,
    const float* __restrict__ lnf_b, const float* __restrict__ head_w,
    const float* __restrict__ head_b, const __bf16* __restrict__ wf,
    float* __restrict__ out) {
  const int tid = threadIdx.x;
  const int lane = tid & 63;
  const int w = tid >> 6;
  const int li16 = lane & 15;
  const int lg = lane >> 4;
  const int col = w * 16 + li16;  // this thread's owned output column

  __shared__ __align__(16) char lds_arena[ARENA_BYTES];
  __bf16(*actA)[APAD] = (__bf16(*)[APAD])(lds_arena + ACT_OFF);
  __bf16(*bufQ)[APAD] = (__bf16(*)[APAD])(lds_arena + BUFQ_OFF);
  __bf16(*bufK)[APAD] = (__bf16(*)[APAD])(lds_arena + BUFK_OFF);
  __bf16* bufT        = (__bf16*)(lds_arena + ACT_OFF);          // V^T [64][82], aliases actA
  float(*hscr)[66]    = (float(*)[66])(lds_arena + BUFQ_OFF);    // aliases bufQ+bufK
  __bf16* sP          = (__bf16*)(lds_arena + SPR_OFF);          // [(b*4+h)*10+qt]*10 + kt
  float* sXf          = (float*)(lds_arena + SPR_OFF);           // 320 f32 (embed only)
  float2(*sPart)[3]   = (float2(*)[3])(lds_arena + SPR_OFF);     // 80x3 f32x2 (LN only)
  float* sGB          = (float*)(lds_arena + SPR_OFF + 2048);    // 128 f32 g|b (LN only)

  // residual in registers: h[mt][r] = h(row=mt*16+lg*4+r, col)
  f32x4 h[MT];

  // -------- LayerNorm on register-h (3 syncs) --------
  auto ln_reg = [&](const float* g, const float* b) {
#pragma unroll
    for (int mt = 0; mt < MT; ++mt)
#pragma unroll
      for (int r = 0; r < 4; ++r) hscr[mt * 16 + lg * 4 + r][col] = h[mt][r];
    if (tid < 64) { sGB[tid] = g[tid]; sGB[64 + tid] = b[tid]; }
    __syncthreads();
    const int row = tid % 80;
    const int c3 = tid / 80;
    const int beg = (c3 == 0) ? 0 : (c3 == 1) ? 22 : 44;
    const int len2 = (c3 < 2) ? 11 : 10;
    if (tid < 240) {
      float s = 0.f, s2 = 0.f;
      for (int k = 0; k < len2; ++k) {
        float2 v = *(const float2*)&hscr[row][beg + 2 * k];
        s += v.x + v.y;
        s2 = fmaf(v.x, v.x, fmaf(v.y, v.y, s2));
      }
      sPart[row][c3] = make_float2(s, s2);
    }
    __syncthreads();
    if (tid < 240) {
      float2 p0 = sPart[row][0], p1 = sPart[row][1], p2 = sPart[row][2];
      float s = p0.x + p1.x + p2.x, s2 = p0.y + p1.y + p2.y;
      float m = s * 0.015625f;
      float rstd = rsqrtf(s2 * 0.015625f - m * m + EPS);
      for (int k = 0; k < len2; ++k) {
        int c = beg + 2 * k;
        float2 v = *(const float2*)&hscr[row][c];
        float v0 = (v.x - m) * rstd * sGB[c] + sGB[64 + c];
        float v1 = (v.y - m) * rstd * sGB[c + 1] + sGB[64 + c + 1];
        *(uint*)&actA[row][c] = pk2(v0, v1);
      }
    }
    __syncthreads();
  };

  // -------- stage x (320 elems, two steps) + embed into registers --------
  {
    const float* xb = x + (size_t)blockIdx.x * (NB * 40);
    sXf[tid] = xb[tid];
    if (tid < NB * 40 - 256) sXf[256 + tid] = xb[256 + tid];
  }
  __syncthreads();
  {
    float ew0 = embed_w[col], ew1 = embed_w[64 + col];
    float ew2 = embed_w[128 + col], ew3 = embed_w[192 + col];
    float eb = embed_b[col];
#pragma unroll
    for (int mt = 0; mt < MT; ++mt)
#pragma unroll
      for (int r = 0; r < 4; ++r) {
        int row = mt * 16 + lg * 4 + r;
        const float* xv = &sXf[(row & 7) * 40 + (row >> 3) * 4];
        float acc = eb;
        acc = fmaf(xv[0], ew0, acc);
        acc = fmaf(xv[1], ew1, acc);
        acc = fmaf(xv[2], ew2, acc);
        acc = fmaf(xv[3], ew3, acc);
        h[mt][r] = acc;
      }
  }
  __syncthreads();

  for (int li = 0; li < 3; ++li) {
    const __bf16* qf = wf + li * 12288;
    const __bf16* pf = wf + PROJF_OFF + li * 4096;
    const __bf16* f1 = wf + F1F_OFF + li * 16384;
    const __bf16* f2 = wf + F2F_OFF + li * 16384;

    // -------- LN1 --------
    ln_reg(&ln1_g[li * 64], &ln1_b[li * 64]);

    // -------- fused QKV GEMM: Q->bufQ, K->bufK, V->regs (packed bf16) --------
    uint2 vpk[MT];
    {
      int4 bq[3][2];
#pragma unroll
      for (int ii = 0; ii < 3; ++ii)
#pragma unroll
        for (int kt = 0; kt < 2; ++kt)
          bq[ii][kt] = ((const int4*)qf)[(kt * 12 + (w + 4 * ii)) * 64 + lane];
#pragma unroll
      for (int mt = 0; mt < MT; ++mt) {
        int arow = mt * 16 + li16;
        int4 a0 = *(const int4*)&actA[arow][lg * 8];
        int4 a1 = *(const int4*)&actA[arow][32 + lg * 8];
        f32x4 aq = {0.f, 0.f, 0.f, 0.f};
        aq = mfma_bf16(a0, bq[0][0], aq);
        aq = mfma_bf16(a1, bq[0][1], aq);
#pragma unroll
        for (int r = 0; r < 4; ++r) bufQ[mt * 16 + lg * 4 + r][col] = (__bf16)aq[r];
        f32x4 ak = {0.f, 0.f, 0.f, 0.f};
        ak = mfma_bf16(a0, bq[1][0], ak);
        ak = mfma_bf16(a1, bq[1][1], ak);
#pragma unroll
        for (int r = 0; r < 4; ++r) bufK[mt * 16 + lg * 4 + r][col] = (__bf16)ak[r];
        f32x4 av = {0.f, 0.f, 0.f, 0.f};
        av = mfma_bf16(a0, bq[2][0], av);
        av = mfma_bf16(a1, bq[2][1], av);
        vpk[mt].x = pk2(av[0], av[1]);
        vpk[mt].y = pk2(av[2], av[3]);
      }
    }
    __syncthreads();

    // -------- scores + softmax (reads Q,K)  ||  V^T write into bufT(actA, dead) ----
    {
      auto do_score = [&](int p) {
        int qt = 2 * p + (lane >> 5);
        int b = lane & 7, hh = (lane >> 3) & 3;
        float qv[16];
        {
          int4 qa = *(const int4*)&bufQ[qt * 8 + b][hh * 16];
          int4 qb = *(const int4*)&bufQ[qt * 8 + b][hh * 16 + 8];
          unpack8(qa, qv); unpack8(qb, qv + 8);
        }
        float sc[10], mx = -1e30f;
#pragma unroll
        for (int kt = 0; kt < 10; ++kt) {
          int4 ka = *(const int4*)&bufK[kt * 8 + b][hh * 16];
          int4 kb = *(const int4*)&bufK[kt * 8 + b][hh * 16 + 8];
          float kv[16]; unpack8(ka, kv); unpack8(kb, kv + 8);
          float d = 0.f;
#pragma unroll
          for (int i = 0; i < 16; ++i) d = fmaf(qv[i], kv[i], d);
          sc[kt] = (kt <= qt) ? d * 0.25f : -1e30f;
          mx = fmaxf(mx, sc[kt]);
        }
        float ssum = 0.f;
#pragma unroll
        for (int kt = 0; kt < 10; ++kt) { sc[kt] = __expf(sc[kt] - mx); ssum += sc[kt]; }
        float inv = __builtin_amdgcn_rcpf(ssum);
        __bf16* prow = &sP[((b * 4 + hh) * 10 + qt) * 10];
#pragma unroll
        for (int kt = 0; kt < 10; ++kt) prow[kt] = (__bf16)(sc[kt] * inv);  // masked -> 0
      };
      if (w == 0) { do_score(0); do_score(4); }
      else do_score(w);
      // V^T: bufT[col][row], two b32 stores per mt (4-byte aligned, odd bank stride)
      const int coff = col * TPITCH;
#pragma unroll
      for (int mt = 0; mt < MT; ++mt) {
        uint* dst = (uint*)&bufT[coff + mt * 16 + lg * 4];
        dst[0] = vpk[mt].x;
        dst[1] = vpk[mt].y;
      }
    }
    __syncthreads();

    // -------- AV: y = P @ V -> bufK (K dead). V-column preloaded to regs. ----
    {
      const int hh = lane >> 4;
      float vcol[2][10];
#pragma unroll
      for (int kt = 0; kt < 10; ++kt) {
        vcol[0][kt] = (float)bufT[lane * TPITCH + kt * 8 + w];
        vcol[1][kt] = (float)bufT[lane * TPITCH + kt * 8 + w + 4];
      }
#pragma unroll
      for (int it = 0; it < 20; ++it) {
        int r = w + 4 * it;
        int b = r & 7, qt = r >> 3, sel = it & 1;
        const __bf16* prow = &sP[((b * 4 + hh) * 10 + qt) * 10];
        float acc = 0.f;
#pragma unroll
        for (int kt = 0; kt < 10; ++kt)
          acc = fmaf((float)prow[kt], vcol[sel][kt], acc);
        bufK[r][lane] = (__bf16)acc;
      }
    }
    __syncthreads();

    // -------- proj (reads y in bufK) + residual into registers --------
    {
      int4 b0 = ((const int4*)pf)[(0 * 4 + w) * 64 + lane];
      int4 b1 = ((const int4*)pf)[(1 * 4 + w) * 64 + lane];
#pragma unroll
      for (int mt = 0; mt < MT; ++mt) {
        int arow = mt * 16 + li16;
        int4 a0 = *(const int4*)&bufK[arow][lg * 8];
        int4 a1 = *(const int4*)&bufK[arow][32 + lg * 8];
        f32x4 acc = {0.f, 0.f, 0.f, 0.f};
        acc = mfma_bf16(a0, b0, acc);
        acc = mfma_bf16(a1, b1, acc);
#pragma unroll
        for (int r = 0; r < 4; ++r) h[mt][r] += acc[r];
      }
    }
    __syncthreads();  // bufK reads done before LN2 s1 overwrites hscr (bufQ+bufK)

    // -------- LN2 --------
    ln_reg(&ln2_g[li * 64], &ln2_b[li * 64]);

    // -------- fused FFN: 2 chunk-pairs --------
    {
#pragma unroll
      for (int cp = 0; cp < 2; ++cp) {
#pragma unroll
        for (int cc = 0; cc < 2; ++cc) {
          int c = cp * 2 + cc;
          int nt1 = c * 4 + w;
          int4 b0 = ((const int4*)f1)[(0 * 16 + nt1) * 64 + lane];
          int4 b1 = ((const int4*)f1)[(1 * 16 + nt1) * 64 + lane];
          float bias1 = ffn_b1[li * 256 + c * 64 + col];
          __bf16(*gbuf)[APAD] = cc ? bufK : bufQ;
#pragma unroll
          for (int mt = 0; mt < MT; ++mt) {
            int arow = mt * 16 + li16;
            int4 a0 = *(const int4*)&actA[arow][lg * 8];
            int4 a1 = *(const int4*)&actA[arow][32 + lg * 8];
            f32x4 acc = {0.f, 0.f, 0.f, 0.f};
            acc = mfma_bf16(a0, b0, acc);
            acc = mfma_bf16(a1, b1, acc);
#pragma unroll
            for (int r = 0; r < 4; ++r)
              gbuf[mt * 16 + lg * 4 + r][col] = (__bf16)gelu_f(acc[r] + bias1);
          }
        }
        __syncthreads();
        f32x4 acc2[MT];
#pragma unroll
        for (int mt = 0; mt < MT; ++mt) acc2[mt] = {0.f, 0.f, 0.f, 0.f};
#pragma unroll
        for (int cc = 0; cc < 2; ++cc) {
          int c = cp * 2 + cc;
          int4 c0 = ((const int4*)f2)[((c * 2 + 0) * 4 + w) * 64 + lane];
          int4 c1 = ((const int4*)f2)[((c * 2 + 1) * 4 + w) * 64 + lane];
          __bf16(*gbuf)[APAD] = cc ? bufK : bufQ;
#pragma unroll
          for (int mt = 0; mt < MT; ++mt) {
            int arow = mt * 16 + li16;
            int4 a0 = *(const int4*)&gbuf[arow][lg * 8];
            int4 a1 = *(const int4*)&gbuf[arow][32 + lg * 8];
            acc2[mt] = mfma_bf16(a0, c0, acc2[mt]);
            acc2[mt] = mfma_bf16(a1, c1, acc2[mt]);
          }
        }
#pragma unroll
        for (int mt = 0; mt < MT; ++mt)
#pragma unroll
          for (int r = 0; r < 4; ++r) h[mt][r] += acc2[mt][r];
        __syncthreads();
      }
      float bias2 = ffn_b2[li * 64 + col];
#pragma unroll
      for (int mt = 0; mt < MT; ++mt)
#pragma unroll
        for (int r = 0; r < 4; ++r) h[mt][r] += bias2;
    }
  }

  // -------- final LN (rows 72..79) + head --------
  if (lg >= 2) {
#pragma unroll
    for (int r = 0; r < 4; ++r) hscr[(lg - 2) * 4 + r][col] = h[4][r];
  }
  __syncthreads();
  float2* sFin = (float2*)(lds_arena + SPR_OFF);
  if (tid < 8) {
    float s = 0.f, s2 = 0.f;
#pragma unroll
    for (int i = 0; i < 64; ++i) { float v = hscr[tid][i]; s += v; s2 = fmaf(v, v, s2); }
    float m = s * 0.015625f;
    sFin[tid] = make_float2(m, rsqrtf(s2 * 0.015625f - m * m + EPS));
  }
  __syncthreads();
  if (tid < 80) {
    int b = tid / 10, j = tid % 10;
    float m = sFin[b].x, rstd = sFin[b].y;
    float acc = head_b[j];
#pragma unroll
    for (int d = 0; d < 64; ++d) {
      float z = (hscr[b][d] - m) * rstd * lnf_g[d] + lnf_b[d];
      acc = fmaf(z, head_w[d * 10 + j], acc);
    }
    out[((size_t)blockIdx.x * NB + b) * 10 + j] = acc;
  }
}

}  // namespace

extern "C" void kernel_launch(void* const* d_in, const int* in_sizes, int n_in,
                              void* d_out, int out_size, void* d_ws, size_t ws_size,
                              hipStream_t stream) {
  const float* x       = (const float*)d_in[0];
  const float* embed_w = (const float*)d_in[1];
  const float* embed_b = (const float*)d_in[2];
  const float* ln1_g   = (const float*)d_in[3];
  const float* ln1_b   = (const float*)d_in[4];
  const float* qkv_w   = (const float*)d_in[5];
  const float* proj_w  = (const float*)d_in[6];
  const float* ln2_g   = (const float*)d_in[7];
  const float* ln2_b   = (const float*)d_in[8];
  const float* ffn_w1  = (const float*)d_in[9];
  const float* ffn_b1  = (const float*)d_in[10];
  const float* ffn_w2  = (const float*)d_in[11];
  const float* ffn_b2  = (const float*)d_in[12];
  const float* lnf_g   = (const float*)d_in[13];
  const float* lnf_b   = (const float*)d_in[14];
  const float* head_w  = (const float*)d_in[15];
  const float* head_b  = (const float*)d_in[16];
  __bf16* wf = (__bf16*)d_ws;
  float* out = (float*)d_out;

  prep_weights<<<dim3((WS_ELEMS + 255) / 256), dim3(256), 0, stream>>>(
      qkv_w, proj_w, ffn_w1, ffn_w2, wf);
  wtf_mfma<<<dim3(NBLK), dim3(256), 0, stream>>>(
      x, embed_w, embed_b, ln1_g, ln1_b, ln2_g, ln2_b, ffn_b1, ffn_b2,
      lnf_g, lnf_b, head_w, head_b, wf, out);
}